// Round 2
// baseline (249.844 us; speedup 1.0000x reference)
//
#include <hip/hip_runtime.h>

// Dense image warp (bilinear), B=8 H=256 W=256 C=64, fp32.
// 4 threads per pixel; thread t handles float4 quads {t, t+4, t+8, t+12}.
// tl/tr share one base address (tr = +256 B immediate); bl/br share base+row.
// 16 independent gathers in flight per thread; 32-bit offsets for saddr form.

__device__ __forceinline__ float4 bilerp4(float4 a, float4 b, float4 c, float4 d,
                                          float ax, float ay) {
    float4 r;
    float top, bot;
    top = fmaf(ax, b.x - a.x, a.x);
    bot = fmaf(ax, d.x - c.x, c.x);
    r.x = fmaf(ay, bot - top, top);
    top = fmaf(ax, b.y - a.y, a.y);
    bot = fmaf(ax, d.y - c.y, c.y);
    r.y = fmaf(ay, bot - top, top);
    top = fmaf(ax, b.z - a.z, a.z);
    bot = fmaf(ax, d.z - c.z, c.z);
    r.z = fmaf(ay, bot - top, top);
    top = fmaf(ax, b.w - a.w, a.w);
    bot = fmaf(ax, d.w - c.w, c.w);
    r.w = fmaf(ay, bot - top, top);
    return r;
}

__global__ __launch_bounds__(256) void warp_bilinear_kernel(
    const float* __restrict__ image,
    const float* __restrict__ flow,
    float* __restrict__ out)
{
    constexpr int H = 256, W = 256;
    constexpr unsigned QUADS = 16;          // float4 per pixel (C=64)
    constexpr unsigned ROWQ = W * QUADS;    // float4 per image row

    const int gid = blockIdx.x * blockDim.x + threadIdx.x;
    const int p = gid >> 2;   // pixel index: b*H*W + y*W + x
    const int t = gid & 3;    // quad-lane within pixel

    const int x = p & (W - 1);
    const int y = (p >> 8) & (H - 1);
    const int b = p >> 16;

    const float2 fl = ((const float2*)flow)[p];
    const float qy = (float)y - fl.x;
    const float qx = (float)x - fl.y;

    // tfa semantics: floor clamped to [0, size-2], alpha clipped to [0,1]
    const float fy = fminf(fmaxf(floorf(qy), 0.0f), (float)(H - 2));
    const float fx = fminf(fmaxf(floorf(qx), 0.0f), (float)(W - 2));
    const float ay = fminf(fmaxf(qy - fy, 0.0f), 1.0f);
    const float ax = fminf(fmaxf(qx - fx, 0.0f), 1.0f);
    const int iy = (int)fy;
    const int ix = (int)fx;

    const float4* __restrict__ img4 = (const float4*)image;

    // float4-unit base offsets (whole image = 8.4M float4 < 2^31)
    const unsigned baseT = (unsigned)(((b * H + iy) * W + ix) * (int)QUADS + t);
    const unsigned baseB = baseT + ROWQ;

    float4 tl[4], tr[4], bl[4], br[4];
    #pragma unroll
    for (int j = 0; j < 4; ++j) tl[j] = img4[baseT + 4u * j];
    #pragma unroll
    for (int j = 0; j < 4; ++j) tr[j] = img4[baseT + QUADS + 4u * j];
    #pragma unroll
    for (int j = 0; j < 4; ++j) bl[j] = img4[baseB + 4u * j];
    #pragma unroll
    for (int j = 0; j < 4; ++j) br[j] = img4[baseB + QUADS + 4u * j];

    float4* __restrict__ out4 = (float4*)out;
    const unsigned obase = (unsigned)(p * (int)QUADS + t);

    #pragma unroll
    for (int j = 0; j < 4; ++j) {
        out4[obase + 4u * j] = bilerp4(tl[j], tr[j], bl[j], br[j], ax, ay);
    }
}

extern "C" void kernel_launch(void* const* d_in, const int* in_sizes, int n_in,
                              void* d_out, int out_size, void* d_ws, size_t ws_size,
                              hipStream_t stream) {
    const float* image = (const float*)d_in[0];
    const float* flow  = (const float*)d_in[1];
    float* out = (float*)d_out;

    constexpr int B = 8, H = 256, W = 256;
    const int total_threads = B * H * W * 4;  // 2,097,152
    const int block = 256;
    const int grid = total_threads / block;   // 8192

    warp_bilinear_kernel<<<grid, block, 0, stream>>>(image, flow, out);
}

// Round 3
// 232.671 us; speedup vs baseline: 1.0738x; 1.0738x over previous
//
#include <hip/hip_runtime.h>

// Dense image warp (bilinear), B=8 H=256 W=256 C=64, fp32.
// 16 threads per pixel (one float4 quad each), TWO adjacent pixels per thread.
// One float4 flow load covers both pixels; 8 independent gathers in flight;
// all load/store instructions cover contiguous 256 B segments per pixel.

__device__ __forceinline__ float4 bilerp4(float4 a, float4 b, float4 c, float4 d,
                                          float ax, float ay) {
    float4 r;
    float top, bot;
    top = fmaf(ax, b.x - a.x, a.x);
    bot = fmaf(ax, d.x - c.x, c.x);
    r.x = fmaf(ay, bot - top, top);
    top = fmaf(ax, b.y - a.y, a.y);
    bot = fmaf(ax, d.y - c.y, c.y);
    r.y = fmaf(ay, bot - top, top);
    top = fmaf(ax, b.z - a.z, a.z);
    bot = fmaf(ax, d.z - c.z, c.z);
    r.z = fmaf(ay, bot - top, top);
    top = fmaf(ax, b.w - a.w, a.w);
    bot = fmaf(ax, d.w - c.w, c.w);
    r.w = fmaf(ay, bot - top, top);
    return r;
}

__global__ __launch_bounds__(256) void warp_bilinear_kernel(
    const float* __restrict__ image,
    const float* __restrict__ flow,
    float* __restrict__ out)
{
    constexpr int H = 256, W = 256;
    constexpr unsigned QUADS = 16;        // float4 per pixel (C=64)
    constexpr unsigned ROWQ = W * QUADS;  // float4 per image row

    const int gid = blockIdx.x * blockDim.x + threadIdx.x;
    const int i = gid >> 4;   // pixel-pair index
    const int t = gid & 15;   // quad within pixel
    const int p0 = i * 2;
    const int p1 = p0 + 1;

    // flow for both pixels in one 16 B load: {fy0, fx0, fy1, fx1}
    const float4 fl = ((const float4*)flow)[i];

    const int x0 = p0 & (W - 1), y0 = (p0 >> 8) & (H - 1), b0 = p0 >> 16;
    const int x1 = p1 & (W - 1), y1 = (p1 >> 8) & (H - 1), b1 = p1 >> 16;

    // query = grid - flow; tfa semantics: floor clamped [0,size-2], alpha [0,1]
    const float qy0 = (float)y0 - fl.x, qx0 = (float)x0 - fl.y;
    const float qy1 = (float)y1 - fl.z, qx1 = (float)x1 - fl.w;

    const float fy0 = fminf(fmaxf(floorf(qy0), 0.0f), (float)(H - 2));
    const float fx0 = fminf(fmaxf(floorf(qx0), 0.0f), (float)(W - 2));
    const float fy1 = fminf(fmaxf(floorf(qy1), 0.0f), (float)(H - 2));
    const float fx1 = fminf(fmaxf(floorf(qx1), 0.0f), (float)(W - 2));
    const float ay0 = fminf(fmaxf(qy0 - fy0, 0.0f), 1.0f);
    const float ax0 = fminf(fmaxf(qx0 - fx0, 0.0f), 1.0f);
    const float ay1 = fminf(fmaxf(qy1 - fy1, 0.0f), 1.0f);
    const float ax1 = fminf(fmaxf(qx1 - fx1, 0.0f), 1.0f);

    const float4* __restrict__ img4 = (const float4*)image;

    const unsigned baseA = (unsigned)(((b0 * H + (int)fy0) * W + (int)fx0) * (int)QUADS + t);
    const unsigned baseB = (unsigned)(((b1 * H + (int)fy1) * W + (int)fx1) * (int)QUADS + t);

    // 8 independent gathers — issue all before any wait
    const float4 Atl = img4[baseA];
    const float4 Atr = img4[baseA + QUADS];
    const float4 Abl = img4[baseA + ROWQ];
    const float4 Abr = img4[baseA + ROWQ + QUADS];
    const float4 Btl = img4[baseB];
    const float4 Btr = img4[baseB + QUADS];
    const float4 Bbl = img4[baseB + ROWQ];
    const float4 Bbr = img4[baseB + ROWQ + QUADS];

    float4* __restrict__ out4 = (float4*)out;
    out4[(unsigned)p0 * QUADS + t] = bilerp4(Atl, Atr, Abl, Abr, ax0, ay0);
    out4[(unsigned)p1 * QUADS + t] = bilerp4(Btl, Btr, Bbl, Bbr, ax1, ay1);
}

extern "C" void kernel_launch(void* const* d_in, const int* in_sizes, int n_in,
                              void* d_out, int out_size, void* d_ws, size_t ws_size,
                              hipStream_t stream) {
    const float* image = (const float*)d_in[0];
    const float* flow  = (const float*)d_in[1];
    float* out = (float*)d_out;

    constexpr int B = 8, H = 256, W = 256;
    const int total_threads = B * H * W * 16 / 2;  // 4,194,304
    const int block = 256;
    const int grid = total_threads / block;        // 16,384

    warp_bilinear_kernel<<<grid, block, 0, stream>>>(image, flow, out);
}